// Round 15
// baseline (14.268 us; speedup 1.0000x reference)
//
#include <hip/hip_runtime.h>

#define NJ 32
#define BLK 256

typedef float f2 __attribute__((ext_vector_type(2)));
__device__ __forceinline__ f2 mk2(float x, float y){ f2 r; r.x=x; r.y=y; return r; }

// ---- Minimal-form segmented (32-lane) inclusive prefix scans ----
// 5 x v_add_f32_dpp per scan; 6-12 independent chains interleaved per asm
// block (dependent DPP ops >=5 slots apart -> hazard-free). bound_ctrl:0
// zeroes out-of-range reads (scan identity); row_bcast:15 row_mask:0xa
// stitches the two 16-lane halves of each 32-lane segment.

#define MODS1 "row_shr:1 row_mask:0xf bank_mask:0xf bound_ctrl:0"
#define MODS2 "row_shr:2 row_mask:0xf bank_mask:0xf bound_ctrl:0"
#define MODS4 "row_shr:4 row_mask:0xf bank_mask:0xf bound_ctrl:0"
#define MODS8 "row_shr:8 row_mask:0xf bank_mask:0xf bound_ctrl:0"
#define MODSB "row_bcast:15 row_mask:0xa bank_mask:0xf"

#define D(n,m) "v_add_f32_dpp %" #n ", %" #n ", %" #n " " m "\n\t"

#define STEP12(m) D(0,m) D(1,m) D(2,m) D(3,m) D(4,m) D(5,m) D(6,m) D(7,m) \
                  D(8,m) D(9,m) D(10,m) D(11,m)
#define STEP6(m)  D(0,m) D(1,m) D(2,m) D(3,m) D(4,m) D(5,m)

__device__ __forceinline__ void scan12(float& a, float& b, float& c, float& d,
                                       float& e, float& f, float& g, float& h,
                                       float& i, float& j, float& k, float& l) {
    asm("s_nop 1\n\t"
        STEP12(MODS1) STEP12(MODS2) STEP12(MODS4) STEP12(MODS8) STEP12(MODSB)
        : "+v"(a), "+v"(b), "+v"(c), "+v"(d), "+v"(e), "+v"(f),
          "+v"(g), "+v"(h), "+v"(i), "+v"(j), "+v"(k), "+v"(l));
}

__device__ __forceinline__ void scan6(float& a, float& b, float& c,
                                      float& d, float& e, float& f) {
    asm("s_nop 1\n\t"
        STEP6(MODS1) STEP6(MODS2) STEP6(MODS4) STEP6(MODS8) STEP6(MODSB)
        : "+v"(a), "+v"(b), "+v"(c), "+v"(d), "+v"(e), "+v"(f));
}

// Segment totals after an inclusive scan live in lanes 31 / 63 (VALU-only).
__device__ __forceinline__ float seg_total(float x, int hiHalf) {
    int lo, hi;
    asm("s_nop 1\n\t"
        "v_readlane_b32 %0, %2, 31\n\t"
        "v_readlane_b32 %1, %2, 63"
        : "=s"(lo), "=s"(hi) : "v"(x));
    return __int_as_float(hiHalf ? hi : lo);
}

// Shift whole wave down one lane (lane i <- lane i-1); wave lane 0 gets 0.
__device__ __forceinline__ float wave_shr1(float x) {
    return __int_as_float(
        __builtin_amdgcn_update_dpp(0, __float_as_int(x), 0x138, 0xf, 0xf, false));
}

// Native HW sincos (revolutions + fract reduction).
__device__ __forceinline__ void fast_sincos(float x, float& s, float& c) {
    float r = __builtin_amdgcn_fractf(x * 0.15915494309189535f);
    s = __builtin_amdgcn_sinf(r);
    c = __builtin_amdgcn_cosf(r);
}

__global__ __launch_bounds__(BLK) void rnea_kernel(
    const float* __restrict__ q,
    const float* __restrict__ qd,
    const float* __restrict__ qdd,
    const float* __restrict__ trans,
    const float* __restrict__ mass,
    const float* __restrict__ com,
    const float* __restrict__ inertia,
    const float* __restrict__ damping,
    float* __restrict__ out,
    int Bn)
{
    const int t    = blockIdx.x * BLK + threadIdx.x;
    const int lane = threadIdx.x & 31;          // joint index
    const int hiH  = (threadIdx.x >> 5) & 1;    // which 32-lane segment
    const int half = Bn >> 1;
    const int r0   = t >> 5;
    if (r0 >= half) return;
    const int i0 = r0 * NJ + lane;              // 32-bit offsets, coalesced
    const int i1 = i0 + half * NJ;

    // Row pair packed as f2 = (row0, row1): all pointwise math identical per
    // row -> clean v_pk_* SIMD2, no component mixing.
    f2 qv   = mk2(q  [i0], q  [i1]);
    f2 qdv  = mk2(qd [i0], qd [i1]);
    f2 qddv = mk2(qdd[i0], qdd[i1]);

    // Per-joint constants (L1-hot broadcast lines), shared by both rows.
    float m    = mass[lane];
    float cx   = com[3*lane+0], cy = com[3*lane+1];
    float mcx  = m*cx, mcy = m*cy;
    float i2zz = fmaf(m, cx*cx + cy*cy, inertia[9*lane+8]);   // Ibar_zz
    float px   = trans[3*lane+0], py = trans[3*lane+1];
    float damp = damping[lane];
    const bool seg0 = (lane == 0);

    // ---- Stage A: 6 prefix scans (phi, w, alpha x 2 rows).
    float phi0 = qv.x,  phi1 = qv.y;
    float wI0  = qdv.x, wI1  = qdv.y;
    float aI0  = qddv.x, aI1 = qddv.y;
    scan6(phi0, phi1, wI0, wI1, aI0, aI1);
    f2 wI = mk2(wI0, wI1), aI = mk2(aI0, aI1);
    f2 wP = wI - qdv;                           // w_{j-1}
    f2 aP = aI - qddv;                          // alpha_{j-1}

    float c0, s0, c1, s1;
    fast_sincos(phi0, s0, c0);
    fast_sincos(phi1, s1, c1);
    f2 c  = mk2(c0, c1), s = mk2(s0, s1);
    f2 cp = mk2(wave_shr1(c0), wave_shr1(c1));
    f2 sp = mk2(wave_shr1(s0), wave_shr1(s1));
    if (seg0) { cp = 1.f; sp = 0.f; }

    // d_j = Rz(phi_{j-1}) * p_j
    f2 dx = cp*px - sp*py;
    f2 dy = sp*px + cp*py;

    // ---- Stage B: 12 prefix scans — VL, S (Abel-collapsed AL), D = prefix(d).
    // ALx = wI*VLy - Sx,  Sx = scan(wP^2*dx + aP*dy)
    // ALy = -wI*VLx - Sy, Sy = scan(wP^2*dy - aP*dx)   [summation by parts]
    f2 w2   = wP*wP;
    f2 ux   = -wP*dy, uy = wP*dx;
    f2 sxin = w2*dx + aP*dy;
    f2 syin = w2*dy - aP*dx;
    float VLx0 = ux.x, VLy0 = uy.x, Sx0 = sxin.x, Sy0 = syin.x, Dx0 = dx.x, Dy0 = dy.x;
    float VLx1 = ux.y, VLy1 = uy.y, Sx1 = sxin.y, Sy1 = syin.y, Dx1 = dx.y, Dy1 = dy.y;
    scan12(VLx0, VLy0, Sx0, Sy0, Dx0, Dy0, VLx1, VLy1, Sx1, Sy1, Dx1, Dy1);
    f2 VLx = mk2(VLx0, VLx1), VLy = mk2(VLy0, VLy1);
    f2 Dx  = mk2(Dx0, Dx1),   Dy  = mk2(Dy0, Dy1);
    f2 ALx = wI*VLy - mk2(Sx0, Sx1);
    f2 ALy = -wI*VLx - mk2(Sy0, Sy1);

    // ---- Backward pointwise (world frame, z-chain only).
    f2 mcwx = c*mcx - s*mcy;                    // Rz(phi_j) * mc
    f2 mcwy = s*mcx + c*mcy;
    f2 fv_lx = m*VLx + wI*mcwy;
    f2 fv_ly = m*VLy - wI*mcwx;
    f2 llx = m*ALx + aI*mcwy - wI*fv_ly;
    f2 lly = m*ALy - aI*mcwx + wI*fv_lx;
    f2 a = aI*i2zz + mcwx*ALy - mcwy*ALx + VLx*fv_ly - VLy*fv_lx;
    f2 e = Dx*lly - Dy*llx;                     // (D x ll)z
    f2 g = a + e;

    // ---- Stage D: 6 prefix scans (llx, lly, g x 2 rows); suffix via totals.
    // Nz_j = suffix(a)_j + suffix(b)_{j+1},  b_k = (d_k x F_k)z.
    // suffix(b)_j = suffix(Dxll)_j - (D_{j-1} x F_j)z   [Abel on suffixes]
    // => Nz_j = suffix(a+e)_j - (D_{j-1} x F_j)z - (d_j x F_j)z
    //         = suffix(a+e)_j - (D_j x F_j)z           [D_{j-1}+d_j = D_j]
    float Plx0 = llx.x, Ply0 = lly.x, Pg0 = g.x;
    float Plx1 = llx.y, Ply1 = lly.y, Pg1 = g.y;
    scan6(Plx0, Ply0, Pg0, Plx1, Ply1, Pg1);
    f2 Tx = mk2(seg_total(Plx0, hiH), seg_total(Plx1, hiH));
    f2 Ty = mk2(seg_total(Ply0, hiH), seg_total(Ply1, hiH));
    f2 Tg = mk2(seg_total(Pg0,  hiH), seg_total(Pg1,  hiH));
    f2 Fx = Tx - mk2(Plx0, Plx1) + llx;
    f2 Fy = Ty - mk2(Ply0, Ply1) + lly;
    f2 sg = Tg - mk2(Pg0,  Pg1)  + g;
    f2 Nz = sg - (Dx*Fy - Dy*Fx);               // D_j, not D_{j-1} (r14 bug)

    f2 tau = damp*qdv + Nz;
    out[i0] = tau.x;
    out[i1] = tau.y;
}

extern "C" void kernel_launch(void* const* d_in, const int* in_sizes, int n_in,
                              void* d_out, int out_size, void* d_ws, size_t ws_size,
                              hipStream_t stream) {
    const float* q       = (const float*)d_in[0];
    const float* qd      = (const float*)d_in[1];
    const float* qdd     = (const float*)d_in[2];
    const float* trans   = (const float*)d_in[3];
    const float* mass    = (const float*)d_in[4];
    const float* com     = (const float*)d_in[5];
    const float* inertia = (const float*)d_in[6];
    const float* damping = (const float*)d_in[7];
    float* out = (float*)d_out;

    int Bn = in_sizes[0] / NJ;
    long long threads = (long long)(Bn/2) * 32;
    int grid = (int)((threads + BLK - 1) / BLK);
    hipLaunchKernelGGL(rnea_kernel, dim3(grid), dim3(BLK), 0, stream,
                       q, qd, qdd, trans, mass, com, inertia, damping, out, Bn);
}

// Round 16
// 13.459 us; speedup vs baseline: 1.0601x; 1.0601x over previous
//
#include <hip/hip_runtime.h>

#define NJ 32
#define BLK 256

typedef float f2 __attribute__((ext_vector_type(2)));
__device__ __forceinline__ f2 mk2(float x, float y){ f2 r; r.x=x; r.y=y; return r; }

// ---- Minimal-form segmented (32-lane) inclusive prefix scans ----
// 5 x v_add_f32_dpp per scan; 2-6 independent chains interleaved per asm
// block so dependent DPP ops are >=2 issue slots apart (gfx9-lineage
// VALU->DPP hazard). bound_ctrl:0 zeroes out-of-range reads (scan identity);
// row_bcast:15 row_mask:0xa stitches the two 16-lane halves of each segment.

#define MODS1 "row_shr:1 row_mask:0xf bank_mask:0xf bound_ctrl:0"
#define MODS2 "row_shr:2 row_mask:0xf bank_mask:0xf bound_ctrl:0"
#define MODS4 "row_shr:4 row_mask:0xf bank_mask:0xf bound_ctrl:0"
#define MODS8 "row_shr:8 row_mask:0xf bank_mask:0xf bound_ctrl:0"
#define MODSB "row_bcast:15 row_mask:0xa bank_mask:0xf"

#define STEP6(m) \
  "v_add_f32_dpp %0, %0, %0 " m "\n\t" \
  "v_add_f32_dpp %1, %1, %1 " m "\n\t" \
  "v_add_f32_dpp %2, %2, %2 " m "\n\t" \
  "v_add_f32_dpp %3, %3, %3 " m "\n\t" \
  "v_add_f32_dpp %4, %4, %4 " m "\n\t" \
  "v_add_f32_dpp %5, %5, %5 " m "\n\t"

#define STEP4(m) \
  "v_add_f32_dpp %0, %0, %0 " m "\n\t" \
  "v_add_f32_dpp %1, %1, %1 " m "\n\t" \
  "v_add_f32_dpp %2, %2, %2 " m "\n\t" \
  "v_add_f32_dpp %3, %3, %3 " m "\n\t"

#define STEP2(m) \
  "v_add_f32_dpp %0, %0, %0 " m "\n\t" \
  "v_add_f32_dpp %1, %1, %1 " m "\n\t" \
  "s_nop 0\n\t"

__device__ __forceinline__ void scan6(float& a, float& b, float& c,
                                      float& d, float& e, float& f) {
    asm("s_nop 1\n\t"
        STEP6(MODS1) STEP6(MODS2) STEP6(MODS4) STEP6(MODS8) STEP6(MODSB)
        : "+v"(a), "+v"(b), "+v"(c), "+v"(d), "+v"(e), "+v"(f));
}

__device__ __forceinline__ void scan4(float& a, float& b, float& c, float& d) {
    asm("s_nop 1\n\t"
        STEP4(MODS1) STEP4(MODS2) STEP4(MODS4) STEP4(MODS8) STEP4(MODSB)
        : "+v"(a), "+v"(b), "+v"(c), "+v"(d));
}

__device__ __forceinline__ void scan2(float& a, float& b) {
    asm("s_nop 1\n\t"
        STEP2(MODS1) STEP2(MODS2) STEP2(MODS4) STEP2(MODS8) STEP2(MODSB)
        : "+v"(a), "+v"(b));
}

// Segment totals after an inclusive scan live in lanes 31 / 63 (VALU-only).
__device__ __forceinline__ float seg_total(float x, int hiHalf) {
    int lo, hi;
    asm("s_nop 1\n\t"
        "v_readlane_b32 %0, %2, 31\n\t"
        "v_readlane_b32 %1, %2, 63"
        : "=s"(lo), "=s"(hi) : "v"(x));
    return __int_as_float(hiHalf ? hi : lo);
}

// Shift whole wave down one lane (lane i <- lane i-1); wave lane 0 gets 0.
__device__ __forceinline__ float wave_shr1(float x) {
    return __int_as_float(
        __builtin_amdgcn_update_dpp(0, __float_as_int(x), 0x138, 0xf, 0xf, false));
}

// Native HW sincos (revolutions + fract reduction).
__device__ __forceinline__ void fast_sincos(float x, float& s, float& c) {
    float r = __builtin_amdgcn_fractf(x * 0.15915494309189535f);
    s = __builtin_amdgcn_sinf(r);
    c = __builtin_amdgcn_cosf(r);
}

__global__ __launch_bounds__(BLK) void rnea_kernel(
    const float* __restrict__ q,
    const float* __restrict__ qd,
    const float* __restrict__ qdd,
    const float* __restrict__ trans,
    const float* __restrict__ mass,
    const float* __restrict__ com,
    const float* __restrict__ inertia,
    const float* __restrict__ damping,
    float* __restrict__ out,
    int Bn)
{
    const int t    = blockIdx.x * BLK + threadIdx.x;
    const int lane = threadIdx.x & 31;          // joint index
    const int hiH  = (threadIdx.x >> 5) & 1;    // which 32-lane segment
    const int half = Bn >> 1;
    const int r0   = t >> 5;
    if (r0 >= half) return;
    const size_t i0 = (size_t)r0 * NJ + lane;   // coalesced
    const size_t i1 = i0 + (size_t)half * NJ;   // coalesced

    // Row pair packed as f2 = (row0, row1); all pointwise math is identical
    // per row -> clean v_pk_* SIMD2, no component mixing ever.
    f2 qv   = mk2(q  [i0], q  [i1]);
    f2 qdv  = mk2(qd [i0], qd [i1]);
    f2 qddv = mk2(qdd[i0], qdd[i1]);

    // Per-joint constants (L1-hot broadcast lines), shared by both rows.
    float m    = mass[lane];
    float cx   = com[3*lane+0], cy = com[3*lane+1];
    float mcx  = m*cx, mcy = m*cy;
    float i2zz = fmaf(m, cx*cx + cy*cy, inertia[9*lane+8]);   // Ibar_zz
    float px   = trans[3*lane+0], py = trans[3*lane+1];
    float damp = damping[lane];
    const bool seg0 = (lane == 0);

    // ---- Stage A: 6 independent prefix scans (phi, w, alpha x 2 rows).
    float phi0 = qv.x,  phi1 = qv.y;
    float wI0  = qdv.x, wI1  = qdv.y;
    float aI0  = qddv.x, aI1 = qddv.y;
    scan6(phi0, phi1, wI0, wI1, aI0, aI1);
    f2 wI = mk2(wI0, wI1), aI = mk2(aI0, aI1);
    f2 wP = wI - qdv;                           // w_{j-1}   (pk)
    f2 aP = aI - qddv;                          // alpha_{j-1}

    float c0, s0, c1, s1;
    fast_sincos(phi0, s0, c0);
    fast_sincos(phi1, s1, c1);
    f2 c  = mk2(c0, c1), s = mk2(s0, s1);
    f2 cp = mk2(wave_shr1(c0), wave_shr1(c1));
    f2 sp = mk2(wave_shr1(s0), wave_shr1(s1));
    if (seg0) { cp = 1.f; sp = 0.f; }

    // d_j = Rz(phi_{j-1}) * p_j    (pk: 2 ops each)
    f2 dx = cp*px - sp*py;
    f2 dy = sp*px + cp*py;

    // ---- Stage B: VL scans (4 chains); integrands pk.
    f2 ux = -wP*dy, uy = wP*dx;
    float VLx0 = ux.x, VLy0 = uy.x, VLx1 = ux.y, VLy1 = uy.y;
    scan4(VLx0, VLy0, VLx1, VLy1);
    f2 VLx = mk2(VLx0, VLx1), VLy = mk2(VLy0, VLy1);

    // ---- Stage C: AL scans (4 chains); integrands pk.
    f2 gx = qdv*VLy - aP*dy;
    f2 gy = -qdv*VLx + aP*dx;
    float ALx0 = gx.x, ALy0 = gy.x, ALx1 = gx.y, ALy1 = gy.y;
    scan4(ALx0, ALy0, ALx1, ALy1);
    f2 ALx = mk2(ALx0, ALx1), ALy = mk2(ALy0, ALy1);

    // ---- Backward (world frame, z-chain only); all pk.
    f2 mcwx = c*mcx - s*mcy;                    // Rz(phi_j) * mc
    f2 mcwy = s*mcx + c*mcy;

    f2 fv_lx = m*VLx + wI*mcwy;
    f2 fv_ly = m*VLy - wI*mcwx;

    f2 llx = m*ALx + aI*mcwy - wI*fv_ly;
    f2 lly = m*ALy - aI*mcwx + wI*fv_lx;

    // ---- Stage D: force prefix scans (4 chains); suffix via totals.
    float Px0 = llx.x, Py0 = lly.x, Px1 = llx.y, Py1 = lly.y;
    scan4(Px0, Py0, Px1, Py1);
    f2 Px = mk2(Px0, Px1), Py = mk2(Py0, Py1);
    f2 Tx = mk2(seg_total(Px0, hiH), seg_total(Px1, hiH));
    f2 Ty = mk2(seg_total(Py0, hiH), seg_total(Py1, hiH));
    f2 Fx = Tx - Px + llx;
    f2 Fy = Ty - Py + lly;

    // ---- Stage E: z-moment chains (2 chains); integrands pk.
    f2 a = aI*i2zz + mcwx*ALy - mcwy*ALx + VLx*fv_ly - VLy*fv_lx;
    f2 b = dx*Fy - dy*Fx;
    f2 ab = a + b;
    float Pr0 = ab.x, Pr1 = ab.y;
    scan2(Pr0, Pr1);
    f2 Pr = mk2(Pr0, Pr1);
    f2 Tr = mk2(seg_total(Pr0, hiH), seg_total(Pr1, hiH));
    // Nz = suffix(a+b) - b = T - Pr + a
    f2 Nz = Tr - Pr + a;

    f2 tau = damp*qdv + Nz;
    out[i0] = tau.x;
    out[i1] = tau.y;
}

extern "C" void kernel_launch(void* const* d_in, const int* in_sizes, int n_in,
                              void* d_out, int out_size, void* d_ws, size_t ws_size,
                              hipStream_t stream) {
    const float* q       = (const float*)d_in[0];
    const float* qd      = (const float*)d_in[1];
    const float* qdd     = (const float*)d_in[2];
    const float* trans   = (const float*)d_in[3];
    const float* mass    = (const float*)d_in[4];
    const float* com     = (const float*)d_in[5];
    const float* inertia = (const float*)d_in[6];
    const float* damping = (const float*)d_in[7];
    float* out = (float*)d_out;

    int Bn = in_sizes[0] / NJ;
    long long threads = (long long)(Bn/2) * 32;
    int grid = (int)((threads + BLK - 1) / BLK);
    hipLaunchKernelGGL(rnea_kernel, dim3(grid), dim3(BLK), 0, stream,
                       q, qd, qdd, trans, mass, com, inertia, damping, out, Bn);
}